// Round 4
// baseline (277.235 us; speedup 1.0000x reference)
//
#include <hip/hip_runtime.h>
#include <math.h>

typedef unsigned int uint;
typedef unsigned short ushort;
typedef __attribute__((ext_vector_type(8))) short short8;
typedef __attribute__((ext_vector_type(4))) float f32x4;

// Problem constants
#define BB  16384
#define DD  64
#define NT_ 128
#define NZ_ 2048
#define NJ_ 2049   // NZ+1

// workspace layout (float offsets)
#define BIAS_OFF 0         // fp32 [64]
#define Q_OFF    64        // fp32 [2048]
#define CC_OFF   2112      // fp32 [2048]
#define INV_OFF  4160      // fp32 [2048]
#define ZB_OFF   6208      // bf16 z    [BB][64]  (524288 float slots)
#define CZB_OFF  530496    // bf16 cz   [NZ][64]
#define WZTB_OFF 596032    // bf16 WzT  [NZ][64]
#define WZB_OFF  661568    // bf16 Wz   [64][NZ]
#define PART_OFF 727104    // fp32 partials [4][64][2049] = 524544
// end 1251648 floats = 5.0 MB

__device__ __forceinline__ ushort f2b(float x) {
  uint u = __float_as_uint(x);
  uint r = (u + 0x7FFFu + ((u >> 16) & 1u)) >> 16;
  return (ushort)r;
}
__device__ __forceinline__ float b2f(ushort h) {
  return __uint_as_float(((uint)h) << 16);
}

// ---------------------------------------------------------------------------
// Kernel 1 (stage 1): split-K partial sums of W_t = einsum('dij,i->dj').
// grid (9, 64, 4): j-chunk 256, d, i-chunk 32. 32 independent dword loads per
// thread, fully unrolled -> BW-bound read of the 67 MB W tensor.
__global__ __launch_bounds__(256) void k_wt1(
    const float* __restrict__ t, const float* __restrict__ ct,
    const float* __restrict__ lst, const float* __restrict__ W,
    float* __restrict__ part)   // [4][64][NJ_]
{
  __shared__ float ph[32];
  int tx = threadIdx.x;
  int d  = blockIdx.y;
  int ic = blockIdx.z;
  if (tx < 32) {
    int i = ic * 32 + tx;
    float r = fabsf(t[0] - ct[i]) * __expf(-lst[i]);
    ph[tx] = __expf(-r * r);
  }
  __syncthreads();
  int j = blockIdx.x * 256 + tx;
  if (j >= NJ_) return;
  const float* Wp = W + (size_t)d * NT_ * NJ_ + (size_t)(ic * 32) * NJ_ + j;
  float acc = 0.f;
#pragma unroll
  for (int k = 0; k < 32; ++k) acc += Wp[(size_t)k * NJ_] * ph[k];
  part[((size_t)ic * 64 + d) * NJ_ + j] = acc;
}

// ---------------------------------------------------------------------------
// Kernel 2 (stage 2): reduce partials -> bf16 Wz + bias; per-centre q/cc/inv;
// bf16 czb[c][d], wztb[c][d]. 32 blocks x 256 thr; 64 centres per block.
__global__ __launch_bounds__(256) void k_prep(
    const float* __restrict__ part, const float* __restrict__ cz,
    const float* __restrict__ lsz,
    float* __restrict__ q, float* __restrict__ cc, float* __restrict__ inv,
    float* __restrict__ bias,
    ushort* __restrict__ wzb, ushort* __restrict__ czb, ushort* __restrict__ wztb)
{
  __shared__ float wtf[64][65];   // [d][c_local] fp32
  int tid = threadIdx.x;
  int cb0 = blockIdx.x * 64;
  // reduce 4 partials for this 64x64 tile; write bf16 wzb + LDS fp32
#pragma unroll
  for (int k = 0; k < 16; ++k) {
    int f = k * 256 + tid;        // 4096 = 64 d x 64 c
    int d = f >> 6, c = f & 63;
    size_t idx = (size_t)d * NJ_ + cb0 + c;
    float s = part[idx] + part[(size_t)64 * NJ_ + idx]
            + part[(size_t)128 * NJ_ + idx] + part[(size_t)192 * NJ_ + idx];
    wtf[d][c] = s;
    wzb[(size_t)d * NZ_ + cb0 + c] = f2b(s);
  }
  if (blockIdx.x == 0 && tid < 64) {
    size_t idx = (size_t)tid * NJ_ + 2048;
    bias[tid] = part[idx] + part[(size_t)64 * NJ_ + idx]
              + part[(size_t)128 * NJ_ + idx] + part[(size_t)192 * NJ_ + idx];
  }
  __syncthreads();
  int c_l = tid >> 2, part4 = tid & 3;   // 4 threads per centre
  int c = cb0 + c_l;
  float qa = 0.f, ca = 0.f;
  ushort czl[16];
  const float4* cz4 = (const float4*)(cz + (size_t)c * DD + part4 * 16);
#pragma unroll
  for (int x = 0; x < 4; ++x) {
    float4 v = cz4[x];
    float va[4] = {v.x, v.y, v.z, v.w};
#pragma unroll
    for (int k = 0; k < 4; ++k) {
      int d = part4 * 16 + x * 4 + k;
      ca += va[k] * va[k];
      qa += wtf[d][c_l] * va[k];
      czl[x * 4 + k] = f2b(va[k]);
    }
  }
  {
    short8 o0, o1;
#pragma unroll
    for (int k = 0; k < 8; ++k) { o0[k] = (short)czl[k]; o1[k] = (short)czl[8 + k]; }
    *(short8*)(czb + (size_t)c * DD + part4 * 16)     = o0;
    *(short8*)(czb + (size_t)c * DD + part4 * 16 + 8) = o1;
  }
  {
    short8 o0, o1;
#pragma unroll
    for (int k = 0; k < 8; ++k) {
      o0[k] = (short)f2b(wtf[part4 * 16 + k][c_l]);
      o1[k] = (short)f2b(wtf[part4 * 16 + 8 + k][c_l]);
    }
    *(short8*)(wztb + (size_t)c * DD + part4 * 16)     = o0;
    *(short8*)(wztb + (size_t)c * DD + part4 * 16 + 8) = o1;
  }
  qa += __shfl_xor(qa, 1); qa += __shfl_xor(qa, 2);
  ca += __shfl_xor(ca, 1); ca += __shfl_xor(ca, 2);
  if (part4 == 0) {
    q[c]  = qa;
    cc[c] = ca;
    inv[c] = __expf(-2.f * lsz[c]);
  }
}

// ---------------------------------------------------------------------------
// Kernel 3: z -> bf16
__global__ __launch_bounds__(256) void k_zb(
    const float* __restrict__ z, ushort* __restrict__ zb)
{
  int f = blockIdx.x * 256 + threadIdx.x;
  const float4* z4 = (const float4*)z;
  float4 v0 = z4[f * 2], v1 = z4[f * 2 + 1];
  short8 o;
  o[0] = (short)f2b(v0.x); o[1] = (short)f2b(v0.y);
  o[2] = (short)f2b(v0.z); o[3] = (short)f2b(v0.w);
  o[4] = (short)f2b(v1.x); o[5] = (short)f2b(v1.y);
  o[6] = (short)f2b(v1.z); o[7] = (short)f2b(v1.w);
  *(short8*)(zb + (size_t)f * 8) = o;
}

// ---------------------------------------------------------------------------
// Main fused MFMA kernel — barrier-free K-loop, 21.5 KB LDS (3 blocks/CU).
// Block: 512 thr = 8 waves = 4-way c-split (ws) x 2 row-halves (h).
// Per-centre scalars read directly from global (L1-resident across blocks).
// Epilogue combine buffer unioned with the phi buffer (disjoint lifetimes).
#define KC 32
#define PH_LD 40

__global__ __launch_bounds__(512, 6) void k_fused(
    const ushort* __restrict__ zb,   // [BB][64] bf16
    const ushort* __restrict__ czb,  // [NZ][64] bf16
    const ushort* __restrict__ wztb, // [NZ][64] bf16
    const ushort* __restrict__ wzb,  // [64][NZ] bf16
    const float* __restrict__ qg, const float* __restrict__ ccg,
    const float* __restrict__ invg, const float* __restrict__ bias,
    float* __restrict__ out)
{
  __shared__ char smem[20480];       // phi [8][2][16][PH_LD] ushort  OR  eps [64][68] float
  __shared__ float dlr[4][64];
  ushort* phs = (ushort*)smem;
  float*  eps = (float*)smem;

  int tid  = threadIdx.x;
  int wv   = tid >> 6, lane = tid & 63;
  int lrow = lane & 15, quad = lane >> 4;
  int ws = wv >> 1;          // c-split group 0..3
  int h  = wv & 1;           // row half 0..1
  int b0 = blockIdx.x * 64;

  // z A-fragments direct from global (2 M-tiles x 2 k-halves)
  short8 a[2][2];
#pragma unroll
  for (int mt = 0; mt < 2; ++mt) {
    const ushort* zr = zb + (size_t)(b0 + h * 32 + mt * 16 + lrow) * DD;
    a[mt][0] = *(const short8*)(zr + quad * 8);
    a[mt][1] = *(const short8*)(zr + 32 + quad * 8);
  }
  // zz per row from fragments + cross-lane reduce
  float zzr[2][4];
#pragma unroll
  for (int mt = 0; mt < 2; ++mt) {
    float p = 0.f;
#pragma unroll
    for (int k = 0; k < 8; ++k) {
      float v0 = b2f((ushort)a[mt][0][k]), v1 = b2f((ushort)a[mt][1][k]);
      p += v0 * v0 + v1 * v1;
    }
    p += __shfl_xor(p, 16);
    p += __shfl_xor(p, 32);
#pragma unroll
    for (int i = 0; i < 4; ++i) zzr[mt][i] = __shfl(p, quad * 4 + i);
  }

  f32x4 acc[2][4];
#pragma unroll
  for (int mt = 0; mt < 2; ++mt)
#pragma unroll
    for (int nt = 0; nt < 4; ++nt) acc[mt][nt] = (f32x4){0.f, 0.f, 0.f, 0.f};
  float dl[2][4] = {{0.f}};

  const f32x4 zero = (f32x4){0.f, 0.f, 0.f, 0.f};
  int cbase = ws * 512;
  int pbase = (wv * 2) * 16 * PH_LD;   // this wave's phi slice (mt-major)
  for (int cc0 = 0; cc0 < 512; cc0 += KC) {
    int c0 = cbase + cc0;
    // ---- GEMM1 + elementwise (2 n-tiles of 16 centres) ----
#pragma unroll
    for (int nt = 0; nt < 2; ++nt) {
      int cl = nt * 16 + lrow, cg = c0 + cl;
      const ushort* cr = czb  + (size_t)cg * DD;
      const ushort* wr = wztb + (size_t)cg * DD;
      short8 bc0 = *(const short8*)(cr + quad * 8);
      short8 bc1 = *(const short8*)(cr + 32 + quad * 8);
      short8 bw0 = *(const short8*)(wr + quad * 8);
      short8 bw1 = *(const short8*)(wr + 32 + quad * 8);
      float ccv = ccg[cg], iv = invg[cg], qv = qg[cg];
#pragma unroll
      for (int mt = 0; mt < 2; ++mt) {
        f32x4 d1 = __builtin_amdgcn_mfma_f32_16x16x32_bf16(a[mt][0], bc0, zero, 0, 0, 0);
        d1       = __builtin_amdgcn_mfma_f32_16x16x32_bf16(a[mt][1], bc1, d1,   0, 0, 0);
        f32x4 d2 = __builtin_amdgcn_mfma_f32_16x16x32_bf16(a[mt][0], bw0, zero, 0, 0, 0);
        d2       = __builtin_amdgcn_mfma_f32_16x16x32_bf16(a[mt][1], bw1, d2,   0, 0, 0);
#pragma unroll
        for (int i = 0; i < 4; ++i) {
          float s = zzr[mt][i] + ccv - 2.f * d1[i];
          s = fmaxf(s, 0.f);
          float p = __expf(-s * iv);
          dl[mt][i] += p * iv * (d2[i] - qv);
          phs[pbase + (mt * 16 + quad * 4 + i) * PH_LD + cl] = f2b(p);
        }
      }
    }
    // ---- GEMM2: dz += phi @ Wz (B direct from global, reused across M-tiles) ----
    short8 ap0 = *(const short8*)&phs[pbase + lrow * PH_LD + quad * 8];
    short8 ap1 = *(const short8*)&phs[pbase + (16 + lrow) * PH_LD + quad * 8];
#pragma unroll
    for (int nt = 0; nt < 4; ++nt) {
      short8 bb = *(const short8*)(wzb + (size_t)(nt * 16 + lrow) * NZ_ + c0 + quad * 8);
      acc[0][nt] = __builtin_amdgcn_mfma_f32_16x16x32_bf16(ap0, bb, acc[0][nt], 0, 0, 0);
      acc[1][nt] = __builtin_amdgcn_mfma_f32_16x16x32_bf16(ap1, bb, acc[1][nt], 0, 0, 0);
    }
  }

  // ---- dl partials (dlr is NOT unioned: safe to write pre-barrier) ----
#pragma unroll
  for (int mt = 0; mt < 2; ++mt)
#pragma unroll
    for (int i = 0; i < 4; ++i) {
      float v = dl[mt][i];
      v += __shfl_xor(v, 1);
      v += __shfl_xor(v, 2);
      v += __shfl_xor(v, 4);
      v += __shfl_xor(v, 8);
      if (lrow == 0) dlr[ws][h * 32 + mt * 16 + quad * 4 + i] = v;
    }

  // ---- dz combine across the 4 c-split groups (eps reuses phi LDS) ----
  for (int s = 0; s < 4; ++s) {
    __syncthreads();
    if (ws == s) {
#pragma unroll
      for (int mt = 0; mt < 2; ++mt)
#pragma unroll
        for (int nt = 0; nt < 4; ++nt)
#pragma unroll
          for (int i = 0; i < 4; ++i) {
            int r = h * 32 + mt * 16 + quad * 4 + i;
            int d = nt * 16 + lrow;
            if (s == 0) eps[r * 68 + d] = acc[mt][nt][i];
            else        eps[r * 68 + d] += acc[mt][nt][i];
          }
    }
  }
  __syncthreads();

  // ---- outputs ----
  {
    int r = tid >> 3, d0 = (tid & 7) * 8;   // 512 thr x 8 floats = 64x64
    float4 e0 = *(const float4*)&eps[r * 68 + d0];
    float4 e1 = *(const float4*)&eps[r * 68 + d0 + 4];
    float4 bv0 = *(const float4*)&bias[d0];
    float4 bv1 = *(const float4*)&bias[d0 + 4];
    float4 o0, o1;
    o0.x = e0.x + bv0.x; o0.y = e0.y + bv0.y; o0.z = e0.z + bv0.z; o0.w = e0.w + bv0.w;
    o1.x = e1.x + bv1.x; o1.y = e1.y + bv1.y; o1.z = e1.z + bv1.z; o1.w = e1.w + bv1.w;
    *(float4*)&out[(size_t)(b0 + r) * DD + d0]     = o0;
    *(float4*)&out[(size_t)(b0 + r) * DD + d0 + 4] = o1;
  }
  if (tid < 64) {
    float s = dlr[0][tid] + dlr[1][tid] + dlr[2][tid] + dlr[3][tid];
    out[(size_t)BB * DD + b0 + tid] = 2.f * s;
  }
}

// ---------------------------------------------------------------------------
extern "C" void kernel_launch(void* const* d_in, const int* in_sizes, int n_in,
                              void* d_out, int out_size, void* d_ws, size_t ws_size,
                              hipStream_t stream)
{
  const float* t   = (const float*)d_in[0];
  const float* z   = (const float*)d_in[1];
  // d_in[2] = logp_z (unused)
  const float* cz  = (const float*)d_in[3];
  const float* lsz = (const float*)d_in[4];
  const float* ct  = (const float*)d_in[5];
  const float* lst = (const float*)d_in[6];
  const float* W   = (const float*)d_in[7];
  float* out = (float*)d_out;
  float* ws  = (float*)d_ws;

  float*  bias = ws + BIAS_OFF;
  float*  q    = ws + Q_OFF;
  float*  cc   = ws + CC_OFF;
  float*  inv  = ws + INV_OFF;
  ushort* zbp  = (ushort*)(ws + ZB_OFF);
  ushort* czb  = (ushort*)(ws + CZB_OFF);
  ushort* wztb = (ushort*)(ws + WZTB_OFF);
  ushort* wzb  = (ushort*)(ws + WZB_OFF);
  float*  part = ws + PART_OFF;

  k_wt1<<<dim3(9, 64, 4), 256, 0, stream>>>(t, ct, lst, W, part);
  k_prep<<<dim3(32), 256, 0, stream>>>(part, cz, lsz, q, cc, inv, bias, wzb, czb, wztb);
  k_zb<<<dim3(512), 256, 0, stream>>>(z, zbp);
  k_fused<<<dim3(BB / 64), 512, 0, stream>>>(zbp, czb, wztb, wzb, q, cc, inv, bias, out);
}

// Round 5
// 209.197 us; speedup vs baseline: 1.3252x; 1.3252x over previous
//
#include <hip/hip_runtime.h>
#include <math.h>

typedef unsigned int uint;
typedef unsigned short ushort;
typedef __attribute__((ext_vector_type(8))) short short8;
typedef __attribute__((ext_vector_type(4))) float f32x4;

// Problem constants
#define BB  16384
#define DD  64
#define NT_ 128
#define NZ_ 2048
#define NJ_ 2049   // NZ+1

// workspace layout (float offsets)
#define BIAS_OFF 0         // fp32 [64]
#define Q_OFF    64        // fp32 [2048]
#define CC_OFF   2112      // fp32 [2048]
#define INV_OFF  4160      // fp32 [2048]
#define ZB_OFF   6208      // bf16 z    [BB][64]  (524288 float slots)
#define CZB_OFF  530496    // bf16 cz   [NZ][64]
#define WZTB_OFF 596032    // bf16 WzT  [NZ][64]
#define WZB_OFF  661568    // bf16 Wz   [64][NZ]
#define PART_OFF 727104    // fp32 partials [4][64][2049] = 524544
// end 1251648 floats = 5.0 MB

__device__ __forceinline__ ushort f2b(float x) {
  uint u = __float_as_uint(x);
  uint r = (u + 0x7FFFu + ((u >> 16) & 1u)) >> 16;
  return (ushort)r;
}
__device__ __forceinline__ ushort f2b_tr(float x) {   // truncation: 1 VALU op
  return (ushort)(__float_as_uint(x) >> 16);
}
__device__ __forceinline__ float b2f(ushort h) {
  return __uint_as_float(((uint)h) << 16);
}

// ---------------------------------------------------------------------------
// Kernel 1 (stage 1): split-K partial sums of W_t = einsum('dij,i->dj').
__global__ __launch_bounds__(256) void k_wt1(
    const float* __restrict__ t, const float* __restrict__ ct,
    const float* __restrict__ lst, const float* __restrict__ W,
    float* __restrict__ part)   // [4][64][NJ_]
{
  __shared__ float ph[32];
  int tx = threadIdx.x;
  int d  = blockIdx.y;
  int ic = blockIdx.z;
  if (tx < 32) {
    int i = ic * 32 + tx;
    float r = fabsf(t[0] - ct[i]) * __expf(-lst[i]);
    ph[tx] = __expf(-r * r);
  }
  __syncthreads();
  int j = blockIdx.x * 256 + tx;
  if (j >= NJ_) return;
  const float* Wp = W + (size_t)d * NT_ * NJ_ + (size_t)(ic * 32) * NJ_ + j;
  float acc = 0.f;
#pragma unroll
  for (int k = 0; k < 32; ++k) acc += Wp[(size_t)k * NJ_] * ph[k];
  part[((size_t)ic * 64 + d) * NJ_ + j] = acc;
}

// ---------------------------------------------------------------------------
// Kernel 2 (stage 2): reduce partials -> bf16 Wz + bias; per-centre q/cc/inv;
// bf16 czb[c][d], wztb[c][d]. 32 blocks x 256 thr; 64 centres per block.
__global__ __launch_bounds__(256) void k_prep(
    const float* __restrict__ part, const float* __restrict__ cz,
    const float* __restrict__ lsz,
    float* __restrict__ q, float* __restrict__ cc, float* __restrict__ inv,
    float* __restrict__ bias,
    ushort* __restrict__ wzb, ushort* __restrict__ czb, ushort* __restrict__ wztb)
{
  __shared__ float wtf[64][65];   // [d][c_local] fp32
  int tid = threadIdx.x;
  int cb0 = blockIdx.x * 64;
#pragma unroll
  for (int k = 0; k < 16; ++k) {
    int f = k * 256 + tid;        // 4096 = 64 d x 64 c
    int d = f >> 6, c = f & 63;
    size_t idx = (size_t)d * NJ_ + cb0 + c;
    float s = part[idx] + part[(size_t)64 * NJ_ + idx]
            + part[(size_t)128 * NJ_ + idx] + part[(size_t)192 * NJ_ + idx];
    wtf[d][c] = s;
    wzb[(size_t)d * NZ_ + cb0 + c] = f2b(s);
  }
  if (blockIdx.x == 0 && tid < 64) {
    size_t idx = (size_t)tid * NJ_ + 2048;
    bias[tid] = part[idx] + part[(size_t)64 * NJ_ + idx]
              + part[(size_t)128 * NJ_ + idx] + part[(size_t)192 * NJ_ + idx];
  }
  __syncthreads();
  int c_l = tid >> 2, part4 = tid & 3;   // 4 threads per centre
  int c = cb0 + c_l;
  float qa = 0.f, ca = 0.f;
  ushort czl[16];
  const float4* cz4 = (const float4*)(cz + (size_t)c * DD + part4 * 16);
#pragma unroll
  for (int x = 0; x < 4; ++x) {
    float4 v = cz4[x];
    float va[4] = {v.x, v.y, v.z, v.w};
#pragma unroll
    for (int k = 0; k < 4; ++k) {
      int d = part4 * 16 + x * 4 + k;
      ca += va[k] * va[k];
      qa += wtf[d][c_l] * va[k];
      czl[x * 4 + k] = f2b(va[k]);
    }
  }
  {
    short8 o0, o1;
#pragma unroll
    for (int k = 0; k < 8; ++k) { o0[k] = (short)czl[k]; o1[k] = (short)czl[8 + k]; }
    *(short8*)(czb + (size_t)c * DD + part4 * 16)     = o0;
    *(short8*)(czb + (size_t)c * DD + part4 * 16 + 8) = o1;
  }
  {
    short8 o0, o1;
#pragma unroll
    for (int k = 0; k < 8; ++k) {
      o0[k] = (short)f2b(wtf[part4 * 16 + k][c_l]);
      o1[k] = (short)f2b(wtf[part4 * 16 + 8 + k][c_l]);
    }
    *(short8*)(wztb + (size_t)c * DD + part4 * 16)     = o0;
    *(short8*)(wztb + (size_t)c * DD + part4 * 16 + 8) = o1;
  }
  qa += __shfl_xor(qa, 1); qa += __shfl_xor(qa, 2);
  ca += __shfl_xor(ca, 1); ca += __shfl_xor(ca, 2);
  if (part4 == 0) {
    q[c]  = qa;
    cc[c] = ca;
    inv[c] = __expf(-2.f * lsz[c]);
  }
}

// ---------------------------------------------------------------------------
// Kernel 3: z -> bf16
__global__ __launch_bounds__(256) void k_zb(
    const float* __restrict__ z, ushort* __restrict__ zb)
{
  int f = blockIdx.x * 256 + threadIdx.x;
  const float4* z4 = (const float4*)z;
  float4 v0 = z4[f * 2], v1 = z4[f * 2 + 1];
  short8 o;
  o[0] = (short)f2b(v0.x); o[1] = (short)f2b(v0.y);
  o[2] = (short)f2b(v0.z); o[3] = (short)f2b(v0.w);
  o[4] = (short)f2b(v1.x); o[5] = (short)f2b(v1.y);
  o[6] = (short)f2b(v1.z); o[7] = (short)f2b(v1.w);
  *(short8*)(zb + (size_t)f * 8) = o;
}

// ---------------------------------------------------------------------------
// Main fused MFMA kernel — barrier-free K-loop, ~10.75 KB LDS.
// Block: 512 thr = 8 waves = 4-way c-split (ws) x 2 row-halves (h); BM=32 rows
// -> grid 512 = 2 blocks/CU resident = 16 waves/CU.
// Per-centre scalars + all B-fragments direct from global (L1/L2-resident).
#define KC 32
#define PH_LD 40

__global__ __launch_bounds__(512) void k_fused(
    const ushort* __restrict__ zb,   // [BB][64] bf16
    const ushort* __restrict__ czb,  // [NZ][64] bf16
    const ushort* __restrict__ wztb, // [NZ][64] bf16
    const ushort* __restrict__ wzb,  // [64][NZ] bf16
    const float* __restrict__ qg, const float* __restrict__ ccg,
    const float* __restrict__ invg, const float* __restrict__ bias,
    float* __restrict__ out)
{
  __shared__ char smem[10240];       // phi [8][16][PH_LD] ushort  OR  eps [32][68] float
  __shared__ float dlr[4][32];
  ushort* phs = (ushort*)smem;
  float*  eps = (float*)smem;

  int tid  = threadIdx.x;
  int wv   = tid >> 6, lane = tid & 63;
  int lrow = lane & 15, quad = lane >> 4;
  int ws = wv >> 1;          // c-split group 0..3
  int h  = wv & 1;           // row half 0..1
  int b0 = blockIdx.x * 32;

  // z A-fragments direct from global (1 M-tile x 2 k-halves)
  short8 a0, a1;
  {
    const ushort* zr = zb + (size_t)(b0 + h * 16 + lrow) * DD;
    a0 = *(const short8*)(zr + quad * 8);
    a1 = *(const short8*)(zr + 32 + quad * 8);
  }
  // zz per row from fragments + cross-lane reduce
  float zzr[4];
  {
    float p = 0.f;
#pragma unroll
    for (int k = 0; k < 8; ++k) {
      float v0 = b2f((ushort)a0[k]), v1 = b2f((ushort)a1[k]);
      p += v0 * v0 + v1 * v1;
    }
    p += __shfl_xor(p, 16);
    p += __shfl_xor(p, 32);
#pragma unroll
    for (int i = 0; i < 4; ++i) zzr[i] = __shfl(p, quad * 4 + i);
  }

  f32x4 acc[4];
#pragma unroll
  for (int nt = 0; nt < 4; ++nt) acc[nt] = (f32x4){0.f, 0.f, 0.f, 0.f};
  float dl[4] = {0.f, 0.f, 0.f, 0.f};

  const f32x4 zero = (f32x4){0.f, 0.f, 0.f, 0.f};
  int cbase = ws * 512;
  int pbase = wv * 16 * PH_LD;
  for (int cc0 = 0; cc0 < 512; cc0 += KC) {
    int c0 = cbase + cc0;
    // ---- GEMM1 + elementwise (2 n-tiles of 16 centres) ----
#pragma unroll
    for (int nt = 0; nt < 2; ++nt) {
      int cl = nt * 16 + lrow, cg = c0 + cl;
      const ushort* cr = czb  + (size_t)cg * DD;
      const ushort* wr = wztb + (size_t)cg * DD;
      short8 bc0 = *(const short8*)(cr + quad * 8);
      short8 bc1 = *(const short8*)(cr + 32 + quad * 8);
      short8 bw0 = *(const short8*)(wr + quad * 8);
      short8 bw1 = *(const short8*)(wr + 32 + quad * 8);
      float ccv = ccg[cg], iv = invg[cg], qv = qg[cg];
      f32x4 d1 = __builtin_amdgcn_mfma_f32_16x16x32_bf16(a0, bc0, zero, 0, 0, 0);
      d1       = __builtin_amdgcn_mfma_f32_16x16x32_bf16(a1, bc1, d1,   0, 0, 0);
      f32x4 d2 = __builtin_amdgcn_mfma_f32_16x16x32_bf16(a0, bw0, zero, 0, 0, 0);
      d2       = __builtin_amdgcn_mfma_f32_16x16x32_bf16(a1, bw1, d2,   0, 0, 0);
#pragma unroll
      for (int i = 0; i < 4; ++i) {
        float s = zzr[i] + ccv - 2.f * d1[i];
        s = fmaxf(s, 0.f);
        float p = __expf(-s * iv);
        dl[i] += p * iv * (d2[i] - qv);
        phs[pbase + (quad * 4 + i) * PH_LD + cl] = f2b_tr(p);
      }
    }
    // ---- GEMM2: dz += phi @ Wz (B direct from global) ----
    short8 ap = *(const short8*)&phs[pbase + lrow * PH_LD + quad * 8];
#pragma unroll
    for (int nt = 0; nt < 4; ++nt) {
      short8 bb = *(const short8*)(wzb + (size_t)(nt * 16 + lrow) * NZ_ + c0 + quad * 8);
      acc[nt] = __builtin_amdgcn_mfma_f32_16x16x32_bf16(ap, bb, acc[nt], 0, 0, 0);
    }
  }

  // ---- dl partials (dlr not unioned; written before the combine barriers) ----
#pragma unroll
  for (int i = 0; i < 4; ++i) {
    float v = dl[i];
    v += __shfl_xor(v, 1);
    v += __shfl_xor(v, 2);
    v += __shfl_xor(v, 4);
    v += __shfl_xor(v, 8);
    if (lrow == 0) dlr[ws][h * 16 + quad * 4 + i] = v;
  }

  // ---- dz combine across the 4 c-split groups (eps reuses phi LDS) ----
  for (int s = 0; s < 4; ++s) {
    __syncthreads();
    if (ws == s) {
#pragma unroll
      for (int nt = 0; nt < 4; ++nt)
#pragma unroll
        for (int i = 0; i < 4; ++i) {
          int r = h * 16 + quad * 4 + i;
          int d = nt * 16 + lrow;
          if (s == 0) eps[r * 68 + d] = acc[nt][i];
          else        eps[r * 68 + d] += acc[nt][i];
        }
    }
  }
  __syncthreads();

  // ---- outputs ----
  {
    int r = tid >> 4, d0 = (tid & 15) * 4;   // 512 thr x 4 floats = 32x64
    float4 e  = *(const float4*)&eps[r * 68 + d0];
    float4 bv = *(const float4*)&bias[d0];
    float4 o;
    o.x = e.x + bv.x; o.y = e.y + bv.y; o.z = e.z + bv.z; o.w = e.w + bv.w;
    *(float4*)&out[(size_t)(b0 + r) * DD + d0] = o;
  }
  if (tid < 32) {
    float s = dlr[0][tid] + dlr[1][tid] + dlr[2][tid] + dlr[3][tid];
    out[(size_t)BB * DD + b0 + tid] = 2.f * s;
  }
}

// ---------------------------------------------------------------------------
extern "C" void kernel_launch(void* const* d_in, const int* in_sizes, int n_in,
                              void* d_out, int out_size, void* d_ws, size_t ws_size,
                              hipStream_t stream)
{
  const float* t   = (const float*)d_in[0];
  const float* z   = (const float*)d_in[1];
  // d_in[2] = logp_z (unused)
  const float* cz  = (const float*)d_in[3];
  const float* lsz = (const float*)d_in[4];
  const float* ct  = (const float*)d_in[5];
  const float* lst = (const float*)d_in[6];
  const float* W   = (const float*)d_in[7];
  float* out = (float*)d_out;
  float* ws  = (float*)d_ws;

  float*  bias = ws + BIAS_OFF;
  float*  q    = ws + Q_OFF;
  float*  cc   = ws + CC_OFF;
  float*  inv  = ws + INV_OFF;
  ushort* zbp  = (ushort*)(ws + ZB_OFF);
  ushort* czb  = (ushort*)(ws + CZB_OFF);
  ushort* wztb = (ushort*)(ws + WZTB_OFF);
  ushort* wzb  = (ushort*)(ws + WZB_OFF);
  float*  part = ws + PART_OFF;

  k_wt1<<<dim3(9, 64, 4), 256, 0, stream>>>(t, ct, lst, W, part);
  k_prep<<<dim3(32), 256, 0, stream>>>(part, cz, lsz, q, cc, inv, bias, wzb, czb, wztb);
  k_zb<<<dim3(512), 256, 0, stream>>>(z, zbp);
  k_fused<<<dim3(BB / 32), 512, 0, stream>>>(zbp, czb, wztb, wzb, q, cc, inv, bias, out);
}

// Round 6
// 145.891 us; speedup vs baseline: 1.9003x; 1.4339x over previous
//
#include <hip/hip_runtime.h>
#include <math.h>

typedef unsigned int uint;
typedef unsigned short ushort;
typedef __attribute__((ext_vector_type(8))) short short8;
typedef __attribute__((ext_vector_type(4))) float f32x4;

// Problem constants
#define BB  16384
#define DD  64
#define NT_ 128
#define NZ_ 2048
#define NJ_ 2049   // NZ+1

// workspace layout (float offsets)
#define BIAS_OFF 0         // fp32 [64]
#define SCS_OFF  64        // float4 [2048] = {cc, inv, q, 0}  (8192 floats)
#define ZB0_OFF  8256      // bf16 z k-half0  [BB][32]  (262144 floats)
#define ZB1_OFF  270400    // bf16 z k-half1  [BB][32]
#define CZ0_OFF  532544    // bf16 cz k0 [NZ][32]  (32768 floats)
#define CZ1_OFF  565312    // bf16 cz k1 [NZ][32]
#define WZT0_OFF 598080    // bf16 WzT k0 [NZ][32]
#define WZT1_OFF 630848    // bf16 WzT k1 [NZ][32]
#define WZBP_OFF 663616    // bf16 Wz packed [64 chunks][64 d][32 c] (65536 floats)
#define PART_OFF 729152    // fp32 partials [4][64][NJ_] = 524544
// end 1253696 floats ~= 5.0 MB

__device__ __forceinline__ ushort f2b(float x) {
  uint u = __float_as_uint(x);
  uint r = (u + 0x7FFFu + ((u >> 16) & 1u)) >> 16;
  return (ushort)r;
}
__device__ __forceinline__ ushort f2b_tr(float x) {   // truncation: 1 VALU op
  return (ushort)(__float_as_uint(x) >> 16);
}
__device__ __forceinline__ float b2f(ushort h) {
  return __uint_as_float(((uint)h) << 16);
}

// ---------------------------------------------------------------------------
// Kernel 1 (stage 1): split-K partial sums of W_t = einsum('dij,i->dj').
__global__ __launch_bounds__(256) void k_wt1(
    const float* __restrict__ t, const float* __restrict__ ct,
    const float* __restrict__ lst, const float* __restrict__ W,
    float* __restrict__ part)   // [4][64][NJ_]
{
  __shared__ float ph[32];
  int tx = threadIdx.x;
  int d  = blockIdx.y;
  int ic = blockIdx.z;
  if (tx < 32) {
    int i = ic * 32 + tx;
    float r = fabsf(t[0] - ct[i]) * __expf(-lst[i]);
    ph[tx] = __expf(-r * r);
  }
  __syncthreads();
  int j = blockIdx.x * 256 + tx;
  if (j >= NJ_) return;
  const float* Wp = W + (size_t)d * NT_ * NJ_ + (size_t)(ic * 32) * NJ_ + j;
  float acc = 0.f;
#pragma unroll
  for (int k = 0; k < 32; ++k) acc += Wp[(size_t)k * NJ_] * ph[k];
  part[((size_t)ic * 64 + d) * NJ_ + j] = acc;
}

// ---------------------------------------------------------------------------
// Kernel 2 (stage 2): 256 blocks x 256 thr, 8 centres/block.
// Reduce partials -> Wt; emit packed bf16 tables + scs float4 + bias.
__global__ __launch_bounds__(256) void k_prep2(
    const float* __restrict__ part, const float* __restrict__ cz,
    const float* __restrict__ lsz,
    float* __restrict__ bias, float4* __restrict__ scs,
    ushort* __restrict__ czb0, ushort* __restrict__ czb1,
    ushort* __restrict__ wzt0, ushort* __restrict__ wzt1,
    ushort* __restrict__ wzbp)
{
  __shared__ float wt[64][9];   // [d][c_local]
  int tid = threadIdx.x;
  int cb0 = blockIdx.x * 8;
#pragma unroll
  for (int h = 0; h < 2; ++h) {
    int f = h * 256 + tid;      // 512 = 64 d x 8 c
    int d = f >> 3, c = f & 7;
    size_t idx = (size_t)d * NJ_ + cb0 + c;
    float s = part[idx] + part[(size_t)64 * NJ_ + idx]
            + part[(size_t)128 * NJ_ + idx] + part[(size_t)192 * NJ_ + idx];
    wt[d][c] = s;
    int cg = cb0 + c;
    wzbp[((size_t)(cg >> 5) * 64 + d) * 32 + (cg & 31)] = f2b(s);
  }
  if (blockIdx.x == 0 && tid < 64) {
    size_t idx = (size_t)tid * NJ_ + 2048;
    bias[tid] = part[idx] + part[(size_t)64 * NJ_ + idx]
              + part[(size_t)128 * NJ_ + idx] + part[(size_t)192 * NJ_ + idx];
  }
  __syncthreads();
  int cl = tid >> 5;            // centre within block 0..7
  int k  = tid & 31;            // 0..31
  int c  = cb0 + cl;
  float cv0 = cz[(size_t)c * DD + k];
  float cv1 = cz[(size_t)c * DD + 32 + k];
  czb0[(size_t)c * 32 + k] = f2b(cv0);
  czb1[(size_t)c * 32 + k] = f2b(cv1);
  float w0 = wt[k][cl], w1 = wt[32 + k][cl];
  wzt0[(size_t)c * 32 + k] = f2b(w0);
  wzt1[(size_t)c * 32 + k] = f2b(w1);
  float ca = cv0 * cv0 + cv1 * cv1;
  float qa = w0 * cv0 + w1 * cv1;
  // reduce across the 32 lanes of this centre-group (aligned within a wave)
  qa += __shfl_xor(qa, 1);  ca += __shfl_xor(ca, 1);
  qa += __shfl_xor(qa, 2);  ca += __shfl_xor(ca, 2);
  qa += __shfl_xor(qa, 4);  ca += __shfl_xor(ca, 4);
  qa += __shfl_xor(qa, 8);  ca += __shfl_xor(ca, 8);
  qa += __shfl_xor(qa, 16); ca += __shfl_xor(ca, 16);
  if (k == 0) scs[c] = make_float4(ca, __expf(-2.f * lsz[c]), qa, 0.f);
}

// ---------------------------------------------------------------------------
// Kernel 3: z -> bf16 k-half-split tables zb0/zb1 [r][32]
__global__ __launch_bounds__(256) void k_zbp(
    const float* __restrict__ z, ushort* __restrict__ zb0, ushort* __restrict__ zb1)
{
  int g = blockIdx.x * 256 + threadIdx.x;   // 0..131071
  int r = g >> 3, seg = g & 7;              // 8 threads per row, 8 elems each
  const float4* zp = (const float4*)(z + (size_t)r * DD + seg * 8);
  float4 v0 = zp[0], v1 = zp[1];
  short8 o;
  o[0] = (short)f2b(v0.x); o[1] = (short)f2b(v0.y);
  o[2] = (short)f2b(v0.z); o[3] = (short)f2b(v0.w);
  o[4] = (short)f2b(v1.x); o[5] = (short)f2b(v1.y);
  o[6] = (short)f2b(v1.z); o[7] = (short)f2b(v1.w);
  ushort* dst = (seg < 4 ? zb0 : zb1) + (size_t)r * 32 + (seg & 3) * 8;
  *(short8*)dst = o;
}

// ---------------------------------------------------------------------------
// Main fused MFMA kernel — barrier-free K-loop, all fragment loads coalesced.
// Block: 256 thr = 4 waves, each wave one c-split group (512 centres) over the
// block's 32 rows (2 M-tiles of 16). Grid 512 -> multiple blocks/CU.
#define PH_LD 40

__global__ __launch_bounds__(256) void k_fused(
    const ushort* __restrict__ zb0, const ushort* __restrict__ zb1,
    const ushort* __restrict__ czb0, const ushort* __restrict__ czb1,
    const ushort* __restrict__ wzt0, const ushort* __restrict__ wzt1,
    const ushort* __restrict__ wzbp,
    const float4* __restrict__ scs, const float* __restrict__ bias,
    float* __restrict__ out)
{
  __shared__ char smem[10240];   // phi [4][32][PH_LD] ushort  OR  eps [32][68] float
  __shared__ float dlr[4][32];
  ushort* phs = (ushort*)smem;
  float*  eps = (float*)smem;

  int tid  = threadIdx.x;
  int ws   = tid >> 6;           // wave = c-split group 0..3
  int lane = tid & 63;
  int lrow = lane & 15, quad = lane >> 4;
  int b0 = blockIdx.x * 32;

  // A-fragments (2 M-tiles x 2 k-halves), coalesced 1 KB loads
  short8 a[2][2];
#pragma unroll
  for (int mt = 0; mt < 2; ++mt) {
    size_t ro = (size_t)(b0 + mt * 16 + lrow) * 32 + quad * 8;
    a[mt][0] = *(const short8*)(zb0 + ro);
    a[mt][1] = *(const short8*)(zb1 + ro);
  }
  // zz per row from fragments + cross-lane reduce
  float zzr[2][4];
#pragma unroll
  for (int mt = 0; mt < 2; ++mt) {
    float p = 0.f;
#pragma unroll
    for (int k = 0; k < 8; ++k) {
      float v0 = b2f((ushort)a[mt][0][k]), v1 = b2f((ushort)a[mt][1][k]);
      p += v0 * v0 + v1 * v1;
    }
    p += __shfl_xor(p, 16);
    p += __shfl_xor(p, 32);      // lane holds zz[row mt*16 + (lane&15)]
#pragma unroll
    for (int i = 0; i < 4; ++i) zzr[mt][i] = __shfl(p, quad * 4 + i);
  }

  f32x4 acc[2][4];
#pragma unroll
  for (int mt = 0; mt < 2; ++mt)
#pragma unroll
    for (int nt = 0; nt < 4; ++nt) acc[mt][nt] = (f32x4){0.f, 0.f, 0.f, 0.f};
  float dl[2][4] = {{0.f}};

  const f32x4 zero = (f32x4){0.f, 0.f, 0.f, 0.f};
  int cbase = ws * 512;
  int pbase = ws * 32 * PH_LD;
  for (int cc0 = 0; cc0 < 512; cc0 += 32) {
    int c0 = cbase + cc0;
    // ---- GEMM1 + elementwise (2 n-tiles of 16 centres) ----
#pragma unroll
    for (int nt = 0; nt < 2; ++nt) {
      int cg = c0 + nt * 16 + lrow;
      size_t ro = (size_t)cg * 32 + quad * 8;
      short8 bc0 = *(const short8*)(czb0 + ro);
      short8 bc1 = *(const short8*)(czb1 + ro);
      short8 bw0 = *(const short8*)(wzt0 + ro);
      short8 bw1 = *(const short8*)(wzt1 + ro);
      float4 sc = scs[cg];       // {cc, inv, q, 0}
#pragma unroll
      for (int mt = 0; mt < 2; ++mt) {
        f32x4 d1 = __builtin_amdgcn_mfma_f32_16x16x32_bf16(a[mt][0], bc0, zero, 0, 0, 0);
        d1       = __builtin_amdgcn_mfma_f32_16x16x32_bf16(a[mt][1], bc1, d1,   0, 0, 0);
        f32x4 d2 = __builtin_amdgcn_mfma_f32_16x16x32_bf16(a[mt][0], bw0, zero, 0, 0, 0);
        d2       = __builtin_amdgcn_mfma_f32_16x16x32_bf16(a[mt][1], bw1, d2,   0, 0, 0);
#pragma unroll
        for (int i = 0; i < 4; ++i) {
          float s = zzr[mt][i] + sc.x - 2.f * d1[i];
          s = fmaxf(s, 0.f);
          float p = __expf(-s * sc.y);
          dl[mt][i] += p * sc.y * (d2[i] - sc.z);
          phs[pbase + (mt * 16 + quad * 4 + i) * PH_LD + nt * 16 + lrow] = f2b_tr(p);
        }
      }
    }
    // ---- GEMM2: dz += phi @ Wz (B from packed chunk table, coalesced) ----
    short8 ap0 = *(const short8*)&phs[pbase + lrow * PH_LD + quad * 8];
    short8 ap1 = *(const short8*)&phs[pbase + (16 + lrow) * PH_LD + quad * 8];
    size_t cb = (size_t)(c0 >> 5) * 64 * 32;
#pragma unroll
    for (int nt = 0; nt < 4; ++nt) {
      short8 bb = *(const short8*)(wzbp + cb + (size_t)(nt * 16 + lrow) * 32 + quad * 8);
      acc[0][nt] = __builtin_amdgcn_mfma_f32_16x16x32_bf16(ap0, bb, acc[0][nt], 0, 0, 0);
      acc[1][nt] = __builtin_amdgcn_mfma_f32_16x16x32_bf16(ap1, bb, acc[1][nt], 0, 0, 0);
    }
  }

  // ---- dl partials (dlr not unioned; safe before combine barriers) ----
#pragma unroll
  for (int mt = 0; mt < 2; ++mt)
#pragma unroll
    for (int i = 0; i < 4; ++i) {
      float v = dl[mt][i];
      v += __shfl_xor(v, 1);
      v += __shfl_xor(v, 2);
      v += __shfl_xor(v, 4);
      v += __shfl_xor(v, 8);
      if (lrow == 0) dlr[ws][mt * 16 + quad * 4 + i] = v;
    }

  // ---- dz combine across the 4 c-split waves (eps reuses phi LDS) ----
  for (int s = 0; s < 4; ++s) {
    __syncthreads();
    if (ws == s) {
#pragma unroll
      for (int mt = 0; mt < 2; ++mt)
#pragma unroll
        for (int nt = 0; nt < 4; ++nt)
#pragma unroll
          for (int i = 0; i < 4; ++i) {
            int r = mt * 16 + quad * 4 + i;
            int d = nt * 16 + lrow;
            if (s == 0) eps[r * 68 + d] = acc[mt][nt][i];
            else        eps[r * 68 + d] += acc[mt][nt][i];
          }
    }
  }
  __syncthreads();

  // ---- outputs ----
  {
    int r = tid >> 3, d0 = (tid & 7) * 8;   // 256 thr x 8 floats = 32x64
    float4 e0 = *(const float4*)&eps[r * 68 + d0];
    float4 e1 = *(const float4*)&eps[r * 68 + d0 + 4];
    float4 bv0 = *(const float4*)&bias[d0];
    float4 bv1 = *(const float4*)&bias[d0 + 4];
    float4 o0, o1;
    o0.x = e0.x + bv0.x; o0.y = e0.y + bv0.y; o0.z = e0.z + bv0.z; o0.w = e0.w + bv0.w;
    o1.x = e1.x + bv1.x; o1.y = e1.y + bv1.y; o1.z = e1.z + bv1.z; o1.w = e1.w + bv1.w;
    *(float4*)&out[(size_t)(b0 + r) * DD + d0]     = o0;
    *(float4*)&out[(size_t)(b0 + r) * DD + d0 + 4] = o1;
  }
  if (tid < 32) {
    float s = dlr[0][tid] + dlr[1][tid] + dlr[2][tid] + dlr[3][tid];
    out[(size_t)BB * DD + b0 + tid] = 2.f * s;
  }
}

// ---------------------------------------------------------------------------
extern "C" void kernel_launch(void* const* d_in, const int* in_sizes, int n_in,
                              void* d_out, int out_size, void* d_ws, size_t ws_size,
                              hipStream_t stream)
{
  const float* t   = (const float*)d_in[0];
  const float* z   = (const float*)d_in[1];
  // d_in[2] = logp_z (unused)
  const float* cz  = (const float*)d_in[3];
  const float* lsz = (const float*)d_in[4];
  const float* ct  = (const float*)d_in[5];
  const float* lst = (const float*)d_in[6];
  const float* W   = (const float*)d_in[7];
  float* out = (float*)d_out;
  float* ws  = (float*)d_ws;

  float*  bias = ws + BIAS_OFF;
  float4* scs  = (float4*)(ws + SCS_OFF);
  ushort* zb0  = (ushort*)(ws + ZB0_OFF);
  ushort* zb1  = (ushort*)(ws + ZB1_OFF);
  ushort* czb0 = (ushort*)(ws + CZ0_OFF);
  ushort* czb1 = (ushort*)(ws + CZ1_OFF);
  ushort* wzt0 = (ushort*)(ws + WZT0_OFF);
  ushort* wzt1 = (ushort*)(ws + WZT1_OFF);
  ushort* wzbp = (ushort*)(ws + WZBP_OFF);
  float*  part = ws + PART_OFF;

  k_wt1<<<dim3(9, 64, 4), 256, 0, stream>>>(t, ct, lst, W, part);
  k_prep2<<<dim3(256), 256, 0, stream>>>(part, cz, lsz, bias, scs,
                                         czb0, czb1, wzt0, wzt1, wzbp);
  k_zbp<<<dim3(512), 256, 0, stream>>>(z, zb0, zb1);
  k_fused<<<dim3(BB / 32), 256, 0, stream>>>(zb0, zb1, czb0, czb1, wzt0, wzt1,
                                             wzbp, scs, bias, out);
}